// Round 6
// baseline (146.855 us; speedup 1.0000x reference)
//
#include <hip/hip_runtime.h>

// DCNv1 forward on MI355X, bf16 MFMA, round 6: K-split occupancy WITHOUT spills.
// B=8, C=128, H=W=64, O=128, 3x3, pad=1 -> Ho=Wo=64.
//
// prep_kernel: blocks 0..511  : x[B][C][H][W] f32 -> xt[B][H][W][C] bf16
//              blocks 512..583: wgt -> wpk MFMA-B-fragment order
//                frag=(tap*4+c0q)*8+nt; lane n=lane&15 (o=nt*16+n), k=quad*8 (c=c0q*32+quad*8)
// dcn_mfma_kernel: grid 1024=(b,ho,woh), 256 thr = 4 waves (mi,kh).
//   Wave = 16-wo m-tile (mi) x N=128, c-half kh (K=576).
//   __launch_bounds__(256,3): VGPR cap ~170 -> NO scratch spill (R5's (256,4)
//   forced a 64-VGPR quantum and spilled: WRITE_SIZE 16->60MB, dur +12us).
//   Corner loads one j-chunk at a time + next-j prefetch to trim live regs.
//   Barrier-free K-loop; B-frags coalesced from global wpk (L2-hot).
//   Epilogue: kh=1 dumps acc to LDS, kh=0 adds, transposes, 64B-contiguous stores.

#define BB 8
#define CC 128
#define HH 64
#define WW 64
#define OO 128
#define KTAPS 9

typedef __attribute__((ext_vector_type(8))) short bf16x8;
typedef __attribute__((ext_vector_type(4))) float f32x4;

__device__ __forceinline__ unsigned short f2bf(float f) {
    unsigned u = __float_as_uint(f);
    u += 0x7FFFu + ((u >> 16) & 1u);   // RNE
    return (unsigned short)(u >> 16);
}
#if __has_builtin(__builtin_amdgcn_cvt_pk_bf16_f32)
typedef __attribute__((ext_vector_type(2))) __bf16 bf16x2_t;
__device__ __forceinline__ unsigned pack2bf(float lo, float hi) {
    bf16x2_t v = __builtin_amdgcn_cvt_pk_bf16_f32(lo, hi);
    unsigned r;
    __builtin_memcpy(&r, &v, 4);
    return r;
}
#else
__device__ __forceinline__ unsigned pack2bf(float lo, float hi) {
    return (unsigned)f2bf(lo) | ((unsigned)f2bf(hi) << 16);
}
#endif
__device__ __forceinline__ float bflo(unsigned p) { return __uint_as_float(p << 16); }
__device__ __forceinline__ float bfhi(unsigned p) { return __uint_as_float(p & 0xFFFF0000u); }

// ---------------- prep: transpose x + pack weights (one launch) ----------------
__global__ __launch_bounds__(256)
void prep_kernel(const float* __restrict__ x, const float* __restrict__ wgt,
                 unsigned short* __restrict__ xt, unsigned short* __restrict__ wpk) {
    const int t = threadIdx.x;
    if (blockIdx.x < 512) {
        __shared__ float tile[WW * 132];
        const int b = blockIdx.x >> 6;
        const int h = blockIdx.x & 63;
        const float* src = x + ((size_t)b * CC * HH + h) * WW;
        {
            const int wq = t & 15;
            const int cb = t >> 4;
#pragma unroll
            for (int it = 0; it < 8; ++it) {
                const int c = it * 16 + cb;
                const float4 v = *reinterpret_cast<const float4*>(src + (size_t)c * (HH * WW) + wq * 4);
                tile[(wq * 4 + 0) * 132 + c] = v.x;
                tile[(wq * 4 + 1) * 132 + c] = v.y;
                tile[(wq * 4 + 2) * 132 + c] = v.z;
                tile[(wq * 4 + 3) * 132 + c] = v.w;
            }
        }
        __syncthreads();
        unsigned short* dst = xt + ((size_t)b * HH + h) * WW * CC;
        {
            const int cg = t & 15;
            const int wb = t >> 4;
#pragma unroll
            for (int it = 0; it < 4; ++it) {
                const int w = it * 16 + wb;
                const float* tp = &tile[w * 132 + cg * 8];
                uint4 p;
                p.x = pack2bf(tp[0], tp[1]);
                p.y = pack2bf(tp[2], tp[3]);
                p.z = pack2bf(tp[4], tp[5]);
                p.w = pack2bf(tp[6], tp[7]);
                *reinterpret_cast<uint4*>(&dst[(size_t)w * CC + cg * 8]) = p;
            }
        }
    } else {
        const int id   = (blockIdx.x - 512) * 256 + t;   // 0..18431
        const int lane = id & 63;
        const int frag = id >> 6;                        // (tap*4 + c0q)*8 + nt
        const int nt   = frag & 7;
        const int c0q  = (frag >> 3) & 3;
        const int tap  = frag >> 5;
        const int o    = (nt << 4) + (lane & 15);
        const int c    = (c0q << 5) + ((lane >> 4) << 3);
        const float* s = wgt + ((size_t)o * CC + c) * KTAPS + tap;
        unsigned u[4];
#pragma unroll
        for (int j = 0; j < 4; ++j)
            u[j] = pack2bf(s[(2 * j) * KTAPS], s[(2 * j + 1) * KTAPS]);
        *reinterpret_cast<uint4*>(wpk + (size_t)frag * 512 + lane * 8) =
            make_uint4(u[0], u[1], u[2], u[3]);
    }
}

// ---------------- main: fused DCN MFMA, K-split 4-wave blocks ----------------
__global__ __launch_bounds__(256, 3)
void dcn_mfma_kernel(const unsigned short* __restrict__ xt,
                     const unsigned short* __restrict__ wpk,
                     const float* __restrict__ offset,
                     const float* __restrict__ bias,
                     float* __restrict__ out) {
    __shared__ __align__(16) float2 sLL[KTAPS * 32];      // 2304 B  (ly,lx)
    __shared__ __align__(16) short2 sYX[KTAPS * 32];      // 1152 B  (y0,x0)
    __shared__ __align__(16) float  dumpf[2 * 2048];      // 16 KB   kh=1 partials
    __shared__ __align__(16) float  transf[2 * 2560];     // 20.5 KB transpose scratch

    const int t   = threadIdx.x;
    const int bid = blockIdx.x;
    const int b   = bid >> 7;
    const int ho  = (bid >> 1) & 63;
    const int woh = bid & 1;

    // ---- sampling records: 9 taps x 32 local wo ----
    for (int s = t; s < KTAPS * 32; s += 256) {
        const int k   = s >> 5;
        const int wol = s & 31;
        const int wo  = (woh << 5) + wol;
        const int ki  = k / 3;
        const int kj  = k - ki * 3;
        const float dy = offset[(((size_t)b * 18 + 2 * k    ) * 64 + ho) * 64 + wo];
        const float dx = offset[(((size_t)b * 18 + 2 * k + 1) * 64 + ho) * 64 + wo];
        const float py = (float)(ho - 1 + ki) + dy;
        const float px = (float)(wo - 1 + kj) + dx;
        const float y0f = floorf(py);
        const float x0f = floorf(px);
        sLL[s] = make_float2(py - y0f, px - x0f);
        sYX[s] = make_short2((short)(int)y0f, (short)(int)x0f);
    }
    __syncthreads();   // records ready; no more block-wide barriers until epilogue

    f32x4 acc[8];
#pragma unroll
    for (int nt = 0; nt < 8; ++nt) acc[nt] = (f32x4){0.f, 0.f, 0.f, 0.f};

    const int lane = t & 63;
    const int wave = t >> 6;
    const int mi   = wave & 1;    // m-tile (16 wo)
    const int kh   = wave >> 1;   // c-half
    const int lm   = lane & 15;
    const int quad = lane >> 4;
    const char* xb = (const char*)(xt + (size_t)b * HH * WW * CC);
    const char* wb = (const char*)wpk;
    const int cbase  = (kh << 7) + (quad << 4);   // byte offset in pixel (j=0)
    const int lane16 = lane * 16;

    for (int tap = 0; tap < KTAPS; ++tap) {
        const int rec = (tap << 5) + (mi << 4) + lm;
        const float2 ll = sLL[rec];
        const short2 yx = sYX[rec];
        const int y0 = yx.x, x0 = yx.y;
        const int y1 = y0 + 1, x1 = x0 + 1;
        const float ly = ll.x, lx = ll.y;
        const bool vy0 = ((unsigned)y0 < (unsigned)HH);
        const bool vy1 = ((unsigned)y1 < (unsigned)HH);
        const bool vx0 = ((unsigned)x0 < (unsigned)WW);
        const bool vx1 = ((unsigned)x1 < (unsigned)WW);
        const float w00 = (vy0 && vx0) ? (1.f - ly) * (1.f - lx) : 0.f;
        const float w01 = (vy0 && vx1) ? (1.f - ly) * lx         : 0.f;
        const float w10 = (vy1 && vx0) ? ly * (1.f - lx)         : 0.f;
        const float w11 = (vy1 && vx1) ? ly * lx                 : 0.f;
        const int cy0 = min(max(y0, 0), HH - 1);
        const int cy1 = min(max(y1, 0), HH - 1);
        const int cx0 = min(max(x0, 0), WW - 1);
        const int cx1 = min(max(x1, 0), WW - 1);
        const char* base00 = xb + ((((cy0 << 6) + cx0) << 8) + cbase);
        const char* base01 = xb + ((((cy0 << 6) + cx1) << 8) + cbase);
        const char* base10 = xb + ((((cy1 << 6) + cx0) << 8) + cbase);
        const char* base11 = xb + ((((cy1 << 6) + cx1) << 8) + cbase);

        // corner loads for j=0 only (16 B x4); j=1 prefetched inside the loop
        uint4 a00 = *reinterpret_cast<const uint4*>(base00);
        uint4 a01 = *reinterpret_cast<const uint4*>(base01);
        uint4 a10 = *reinterpret_cast<const uint4*>(base10);
        uint4 a11 = *reinterpret_cast<const uint4*>(base11);

        const char* wtap = wb + ((((tap << 2) + (kh << 1)) << 13)) + lane16;

#pragma unroll
        for (int j = 0; j < 2; ++j) {
            uint4 bfr[8];
            const char* wrow = wtap + (j << 13);
#pragma unroll
            for (int nt = 0; nt < 8; ++nt)
                bfr[nt] = *reinterpret_cast<const uint4*>(wrow + (nt << 10));

            uint4 n00, n01, n10, n11;
            if (j == 0) {
                n00 = *reinterpret_cast<const uint4*>(base00 + 64);
                n01 = *reinterpret_cast<const uint4*>(base01 + 64);
                n10 = *reinterpret_cast<const uint4*>(base10 + 64);
                n11 = *reinterpret_cast<const uint4*>(base11 + 64);
            }

            const unsigned* u00 = reinterpret_cast<const unsigned*>(&a00);
            const unsigned* u01 = reinterpret_cast<const unsigned*>(&a01);
            const unsigned* u10 = reinterpret_cast<const unsigned*>(&a10);
            const unsigned* u11 = reinterpret_cast<const unsigned*>(&a11);
            unsigned afu[4];
#pragma unroll
            for (int jj = 0; jj < 4; ++jj) {
                const float rl = w00 * bflo(u00[jj]) + w01 * bflo(u01[jj])
                               + w10 * bflo(u10[jj]) + w11 * bflo(u11[jj]);
                const float rh = w00 * bfhi(u00[jj]) + w01 * bfhi(u01[jj])
                               + w10 * bfhi(u10[jj]) + w11 * bfhi(u11[jj]);
                afu[jj] = pack2bf(rl, rh);
            }
            bf16x8 afrag;
            __builtin_memcpy(&afrag, afu, 16);
#pragma unroll
            for (int nt = 0; nt < 8; ++nt) {
                bf16x8 bfrag;
                __builtin_memcpy(&bfrag, &bfr[nt], 16);
                acc[nt] = __builtin_amdgcn_mfma_f32_16x16x32_bf16(afrag, bfrag, acc[nt], 0, 0, 0);
            }
            if (j == 0) { a00 = n00; a01 = n01; a10 = n10; a11 = n11; }
        }
    }

    // ---- epilogue: kh-reduction, transpose, 64B-contiguous stores ----
    if (kh == 1) {
        float* d = dumpf + mi * 2048;
#pragma unroll
        for (int nt = 0; nt < 8; ++nt)
            *reinterpret_cast<float4*>(&d[((nt << 6) + lane) << 2]) =
                make_float4(acc[nt][0], acc[nt][1], acc[nt][2], acc[nt][3]);
    }
    __syncthreads();
    if (kh == 0) {
        const float* d = dumpf + mi * 2048;
#pragma unroll
        for (int nt = 0; nt < 8; ++nt) {
            const float4 p = *reinterpret_cast<const float4*>(&d[((nt << 6) + lane) << 2]);
            acc[nt][0] += p.x; acc[nt][1] += p.y; acc[nt][2] += p.z; acc[nt][3] += p.w;
        }
        float* scr = transf + mi * 2560;
#pragma unroll
        for (int nt = 0; nt < 8; ++nt) {
            const int o_l = (nt << 4) + lm;
            *reinterpret_cast<float4*>(&scr[o_l * 20 + (quad << 2)]) =
                make_float4(acc[nt][0], acc[nt][1], acc[nt][2], acc[nt][3]);
        }
#pragma unroll
        for (int h = 0; h < 2; ++h) {
            const int o = (h << 6) + lane;
            const float bv = bias[o];
            float* op = out + (((size_t)(b * OO + o) * HH + ho) << 6) + (woh << 5) + (mi << 4);
            const float* sr = scr + o * 20;
#pragma unroll
            for (int jj = 0; jj < 4; ++jj) {
                const float4 f = *reinterpret_cast<const float4*>(sr + jj * 4);
                *reinterpret_cast<float4*>(op + jj * 4) =
                    make_float4(f.x + bv, f.y + bv, f.z + bv, f.w + bv);
            }
        }
    }
}

extern "C" void kernel_launch(void* const* d_in, const int* in_sizes, int n_in,
                              void* d_out, int out_size, void* d_ws, size_t ws_size,
                              hipStream_t stream) {
    const float* x      = (const float*)d_in[0];
    const float* offset = (const float*)d_in[1];
    const float* wgt    = (const float*)d_in[2];
    const float* bias   = (const float*)d_in[3];
    float* out = (float*)d_out;

    unsigned short* xt  = (unsigned short*)d_ws;                  // 8 MiB
    unsigned short* wpk = xt + (size_t)BB * HH * WW * CC;         // +288 KiB

    hipLaunchKernelGGL(prep_kernel, dim3(512 + 72), dim3(256), 0, stream, x, wgt, xt, wpk);
    hipLaunchKernelGGL(dcn_mfma_kernel, dim3(BB * HH * 2), dim3(256), 0, stream,
                       xt, wpk, offset, bias, out);
}

// Round 7
// 144.372 us; speedup vs baseline: 1.0172x; 1.0172x over previous
//
#include <hip/hip_runtime.h>

// DCNv1 forward on MI355X, bf16 MFMA, round 7: R6 body + (256,4) -> even 4 blocks/CU.
// B=8, C=128, H=W=64, O=128, 3x3, pad=1 -> Ho=Wo=64.
//
// R6 post-mortem: (256,3) capped 3 blocks/CU but grid=1024 needs 4 -> 256-block tail
// at 1 block/CU erased the occupancy win. Body is 68 VGPR + 32 AGPR = 100 combined,
// which fits the 4-waves/SIMD cap (512/4 = 128); LDS 40448 <= 40960 -> 4 blocks/CU.
// So: identical kernel, __launch_bounds__(256,4). Grid 1024 = exactly 4/CU, no tail.
//
// prep_kernel: blocks 0..511  : x[B][C][H][W] f32 -> xt[B][H][W][C] bf16
//              blocks 512..583: wgt -> wpk MFMA-B-fragment order
// dcn_mfma_kernel: grid 1024=(b,ho,woh), 4 waves (mi,kh): 16-wo m-tile x N=128,
//   c-half kh. Barrier-free K-loop; A-frags from 4 scattered uint4 corner loads
//   (j=1 prefetched); B-frags coalesced from global wpk (L2-hot).
//   Epilogue: kh=1 dumps acc to LDS, kh=0 adds, transposes, 64B-contiguous stores.

#define BB 8
#define CC 128
#define HH 64
#define WW 64
#define OO 128
#define KTAPS 9

typedef __attribute__((ext_vector_type(8))) short bf16x8;
typedef __attribute__((ext_vector_type(4))) float f32x4;

__device__ __forceinline__ unsigned short f2bf(float f) {
    unsigned u = __float_as_uint(f);
    u += 0x7FFFu + ((u >> 16) & 1u);   // RNE
    return (unsigned short)(u >> 16);
}
#if __has_builtin(__builtin_amdgcn_cvt_pk_bf16_f32)
typedef __attribute__((ext_vector_type(2))) __bf16 bf16x2_t;
__device__ __forceinline__ unsigned pack2bf(float lo, float hi) {
    bf16x2_t v = __builtin_amdgcn_cvt_pk_bf16_f32(lo, hi);
    unsigned r;
    __builtin_memcpy(&r, &v, 4);
    return r;
}
#else
__device__ __forceinline__ unsigned pack2bf(float lo, float hi) {
    return (unsigned)f2bf(lo) | ((unsigned)f2bf(hi) << 16);
}
#endif
__device__ __forceinline__ float bflo(unsigned p) { return __uint_as_float(p << 16); }
__device__ __forceinline__ float bfhi(unsigned p) { return __uint_as_float(p & 0xFFFF0000u); }

// ---------------- prep: transpose x + pack weights (one launch) ----------------
__global__ __launch_bounds__(256)
void prep_kernel(const float* __restrict__ x, const float* __restrict__ wgt,
                 unsigned short* __restrict__ xt, unsigned short* __restrict__ wpk) {
    const int t = threadIdx.x;
    if (blockIdx.x < 512) {
        __shared__ float tile[WW * 132];
        const int b = blockIdx.x >> 6;
        const int h = blockIdx.x & 63;
        const float* src = x + ((size_t)b * CC * HH + h) * WW;
        {
            const int wq = t & 15;
            const int cb = t >> 4;
#pragma unroll
            for (int it = 0; it < 8; ++it) {
                const int c = it * 16 + cb;
                const float4 v = *reinterpret_cast<const float4*>(src + (size_t)c * (HH * WW) + wq * 4);
                tile[(wq * 4 + 0) * 132 + c] = v.x;
                tile[(wq * 4 + 1) * 132 + c] = v.y;
                tile[(wq * 4 + 2) * 132 + c] = v.z;
                tile[(wq * 4 + 3) * 132 + c] = v.w;
            }
        }
        __syncthreads();
        unsigned short* dst = xt + ((size_t)b * HH + h) * WW * CC;
        {
            const int cg = t & 15;
            const int wb = t >> 4;
#pragma unroll
            for (int it = 0; it < 4; ++it) {
                const int w = it * 16 + wb;
                const float* tp = &tile[w * 132 + cg * 8];
                uint4 p;
                p.x = pack2bf(tp[0], tp[1]);
                p.y = pack2bf(tp[2], tp[3]);
                p.z = pack2bf(tp[4], tp[5]);
                p.w = pack2bf(tp[6], tp[7]);
                *reinterpret_cast<uint4*>(&dst[(size_t)w * CC + cg * 8]) = p;
            }
        }
    } else {
        const int id   = (blockIdx.x - 512) * 256 + t;   // 0..18431
        const int lane = id & 63;
        const int frag = id >> 6;                        // (tap*4 + c0q)*8 + nt
        const int nt   = frag & 7;
        const int c0q  = (frag >> 3) & 3;
        const int tap  = frag >> 5;
        const int o    = (nt << 4) + (lane & 15);
        const int c    = (c0q << 5) + ((lane >> 4) << 3);
        const float* s = wgt + ((size_t)o * CC + c) * KTAPS + tap;
        unsigned u[4];
#pragma unroll
        for (int j = 0; j < 4; ++j)
            u[j] = pack2bf(s[(2 * j) * KTAPS], s[(2 * j + 1) * KTAPS]);
        *reinterpret_cast<uint4*>(wpk + (size_t)frag * 512 + lane * 8) =
            make_uint4(u[0], u[1], u[2], u[3]);
    }
}

// ---------------- main: fused DCN MFMA, K-split 4-wave blocks ----------------
__global__ __launch_bounds__(256, 4)
void dcn_mfma_kernel(const unsigned short* __restrict__ xt,
                     const unsigned short* __restrict__ wpk,
                     const float* __restrict__ offset,
                     const float* __restrict__ bias,
                     float* __restrict__ out) {
    __shared__ __align__(16) float2 sLL[KTAPS * 32];      // 2304 B  (ly,lx)
    __shared__ __align__(16) short2 sYX[KTAPS * 32];      // 1152 B  (y0,x0)
    __shared__ __align__(16) float  dumpf[2 * 2048];      // 16 KB   kh=1 partials
    __shared__ __align__(16) float  transf[2 * 2560];     // 20.5 KB transpose scratch

    const int t   = threadIdx.x;
    const int bid = blockIdx.x;
    const int b   = bid >> 7;
    const int ho  = (bid >> 1) & 63;
    const int woh = bid & 1;

    // ---- sampling records: 9 taps x 32 local wo ----
    for (int s = t; s < KTAPS * 32; s += 256) {
        const int k   = s >> 5;
        const int wol = s & 31;
        const int wo  = (woh << 5) + wol;
        const int ki  = k / 3;
        const int kj  = k - ki * 3;
        const float dy = offset[(((size_t)b * 18 + 2 * k    ) * 64 + ho) * 64 + wo];
        const float dx = offset[(((size_t)b * 18 + 2 * k + 1) * 64 + ho) * 64 + wo];
        const float py = (float)(ho - 1 + ki) + dy;
        const float px = (float)(wo - 1 + kj) + dx;
        const float y0f = floorf(py);
        const float x0f = floorf(px);
        sLL[s] = make_float2(py - y0f, px - x0f);
        sYX[s] = make_short2((short)(int)y0f, (short)(int)x0f);
    }
    __syncthreads();   // records ready; no more block-wide barriers until epilogue

    f32x4 acc[8];
#pragma unroll
    for (int nt = 0; nt < 8; ++nt) acc[nt] = (f32x4){0.f, 0.f, 0.f, 0.f};

    const int lane = t & 63;
    const int wave = t >> 6;
    const int mi   = wave & 1;    // m-tile (16 wo)
    const int kh   = wave >> 1;   // c-half
    const int lm   = lane & 15;
    const int quad = lane >> 4;
    const char* xb = (const char*)(xt + (size_t)b * HH * WW * CC);
    const char* wb = (const char*)wpk;
    const int cbase  = (kh << 7) + (quad << 4);   // byte offset in pixel (j=0)
    const int lane16 = lane * 16;

    for (int tap = 0; tap < KTAPS; ++tap) {
        const int rec = (tap << 5) + (mi << 4) + lm;
        const float2 ll = sLL[rec];
        const short2 yx = sYX[rec];
        const int y0 = yx.x, x0 = yx.y;
        const int y1 = y0 + 1, x1 = x0 + 1;
        const float ly = ll.x, lx = ll.y;
        const bool vy0 = ((unsigned)y0 < (unsigned)HH);
        const bool vy1 = ((unsigned)y1 < (unsigned)HH);
        const bool vx0 = ((unsigned)x0 < (unsigned)WW);
        const bool vx1 = ((unsigned)x1 < (unsigned)WW);
        const float w00 = (vy0 && vx0) ? (1.f - ly) * (1.f - lx) : 0.f;
        const float w01 = (vy0 && vx1) ? (1.f - ly) * lx         : 0.f;
        const float w10 = (vy1 && vx0) ? ly * (1.f - lx)         : 0.f;
        const float w11 = (vy1 && vx1) ? ly * lx                 : 0.f;
        const int cy0 = min(max(y0, 0), HH - 1);
        const int cy1 = min(max(y1, 0), HH - 1);
        const int cx0 = min(max(x0, 0), WW - 1);
        const int cx1 = min(max(x1, 0), WW - 1);
        const char* base00 = xb + ((((cy0 << 6) + cx0) << 8) + cbase);
        const char* base01 = xb + ((((cy0 << 6) + cx1) << 8) + cbase);
        const char* base10 = xb + ((((cy1 << 6) + cx0) << 8) + cbase);
        const char* base11 = xb + ((((cy1 << 6) + cx1) << 8) + cbase);

        // corner loads for j=0 only (16 B x4); j=1 prefetched inside the loop
        uint4 a00 = *reinterpret_cast<const uint4*>(base00);
        uint4 a01 = *reinterpret_cast<const uint4*>(base01);
        uint4 a10 = *reinterpret_cast<const uint4*>(base10);
        uint4 a11 = *reinterpret_cast<const uint4*>(base11);

        const char* wtap = wb + ((((tap << 2) + (kh << 1)) << 13)) + lane16;

#pragma unroll
        for (int j = 0; j < 2; ++j) {
            uint4 bfr[8];
            const char* wrow = wtap + (j << 13);
#pragma unroll
            for (int nt = 0; nt < 8; ++nt)
                bfr[nt] = *reinterpret_cast<const uint4*>(wrow + (nt << 10));

            uint4 n00, n01, n10, n11;
            if (j == 0) {
                n00 = *reinterpret_cast<const uint4*>(base00 + 64);
                n01 = *reinterpret_cast<const uint4*>(base01 + 64);
                n10 = *reinterpret_cast<const uint4*>(base10 + 64);
                n11 = *reinterpret_cast<const uint4*>(base11 + 64);
            }

            const unsigned* u00 = reinterpret_cast<const unsigned*>(&a00);
            const unsigned* u01 = reinterpret_cast<const unsigned*>(&a01);
            const unsigned* u10 = reinterpret_cast<const unsigned*>(&a10);
            const unsigned* u11 = reinterpret_cast<const unsigned*>(&a11);
            unsigned afu[4];
#pragma unroll
            for (int jj = 0; jj < 4; ++jj) {
                const float rl = w00 * bflo(u00[jj]) + w01 * bflo(u01[jj])
                               + w10 * bflo(u10[jj]) + w11 * bflo(u11[jj]);
                const float rh = w00 * bfhi(u00[jj]) + w01 * bfhi(u01[jj])
                               + w10 * bfhi(u10[jj]) + w11 * bfhi(u11[jj]);
                afu[jj] = pack2bf(rl, rh);
            }
            bf16x8 afrag;
            __builtin_memcpy(&afrag, afu, 16);
#pragma unroll
            for (int nt = 0; nt < 8; ++nt) {
                bf16x8 bfrag;
                __builtin_memcpy(&bfrag, &bfr[nt], 16);
                acc[nt] = __builtin_amdgcn_mfma_f32_16x16x32_bf16(afrag, bfrag, acc[nt], 0, 0, 0);
            }
            if (j == 0) { a00 = n00; a01 = n01; a10 = n10; a11 = n11; }
        }
    }

    // ---- epilogue: kh-reduction, transpose, 64B-contiguous stores ----
    if (kh == 1) {
        float* d = dumpf + mi * 2048;
#pragma unroll
        for (int nt = 0; nt < 8; ++nt)
            *reinterpret_cast<float4*>(&d[((nt << 6) + lane) << 2]) =
                make_float4(acc[nt][0], acc[nt][1], acc[nt][2], acc[nt][3]);
    }
    __syncthreads();
    if (kh == 0) {
        const float* d = dumpf + mi * 2048;
#pragma unroll
        for (int nt = 0; nt < 8; ++nt) {
            const float4 p = *reinterpret_cast<const float4*>(&d[((nt << 6) + lane) << 2]);
            acc[nt][0] += p.x; acc[nt][1] += p.y; acc[nt][2] += p.z; acc[nt][3] += p.w;
        }
        float* scr = transf + mi * 2560;
#pragma unroll
        for (int nt = 0; nt < 8; ++nt) {
            const int o_l = (nt << 4) + lm;
            *reinterpret_cast<float4*>(&scr[o_l * 20 + (quad << 2)]) =
                make_float4(acc[nt][0], acc[nt][1], acc[nt][2], acc[nt][3]);
        }
#pragma unroll
        for (int h = 0; h < 2; ++h) {
            const int o = (h << 6) + lane;
            const float bv = bias[o];
            float* op = out + (((size_t)(b * OO + o) * HH + ho) << 6) + (woh << 5) + (mi << 4);
            const float* sr = scr + o * 20;
#pragma unroll
            for (int jj = 0; jj < 4; ++jj) {
                const float4 f = *reinterpret_cast<const float4*>(sr + jj * 4);
                *reinterpret_cast<float4*>(op + jj * 4) =
                    make_float4(f.x + bv, f.y + bv, f.z + bv, f.w + bv);
            }
        }
    }
}

extern "C" void kernel_launch(void* const* d_in, const int* in_sizes, int n_in,
                              void* d_out, int out_size, void* d_ws, size_t ws_size,
                              hipStream_t stream) {
    const float* x      = (const float*)d_in[0];
    const float* offset = (const float*)d_in[1];
    const float* wgt    = (const float*)d_in[2];
    const float* bias   = (const float*)d_in[3];
    float* out = (float*)d_out;

    unsigned short* xt  = (unsigned short*)d_ws;                  // 8 MiB
    unsigned short* wpk = xt + (size_t)BB * HH * WW * CC;         // +288 KiB

    hipLaunchKernelGGL(prep_kernel, dim3(512 + 72), dim3(256), 0, stream, x, wgt, xt, wpk);
    hipLaunchKernelGGL(dcn_mfma_kernel, dim3(BB * HH * 2), dim3(256), 0, stream,
                       xt, wpk, offset, bias, out);
}

// Round 8
// 140.364 us; speedup vs baseline: 1.0462x; 1.0286x over previous
//
#include <hip/hip_runtime.h>

// DCNv1 forward on MI355X, bf16 MFMA, round 8.
// B=8, C=128, H=W=64, O=128, 3x3, pad=1 -> Ho=Wo=64.
//
// R5/R7 lesson: forcing min-waves=4 via __launch_bounds__ makes the allocator
// round this body's ~100 combined regs down to 64 VGPR -> K-loop spills
// (WRITE_SIZE 16->60MB). So: get 16 waves/CU with NATURAL allocation instead:
//   128-thread blocks = one kh-pair (K-split halves) per 16-wo m-tile.
//   Grid 2048 = 4096 waves total = 16 waves/CU of work; no launch_bounds cap.
// XCD swizzle: b = bid & 7 pins batch b to one XCD -> x_t[b] (1MB) + wpk
//   (288KB) are L2-resident -> gather latency ~200cyc instead of ~900.
//
// prep_kernel: blocks 0..511: x -> xt[B][H][W][C] bf16; 512..583: wgt -> wpk
//   (MFMA B-frag order: frag=(tap*4+c0q)*8+nt, 1KB each, lane*16B inside).
// dcn_mfma_kernel: bid -> b=bid&7, s=bid>>3: ho=s>>2, mt=s&3 (16-wo tile).
//   2 waves (kh = c-half). Barrier-free K-loop: 9 taps x 2 j-chunks;
//   A-frags from 4 scattered uint4 corner loads (j=1 prefetched), B-frags
//   coalesced from global wpk. Epilogue: kh=1 dumps acc to LDS, kh=0 adds +
//   writes back, both waves store transposed 64B-contiguous runs (o-half each).

#define BB 8
#define CC 128
#define HH 64
#define WW 64
#define OO 128
#define KTAPS 9

typedef __attribute__((ext_vector_type(8))) short bf16x8;
typedef __attribute__((ext_vector_type(4))) float f32x4;

__device__ __forceinline__ unsigned short f2bf(float f) {
    unsigned u = __float_as_uint(f);
    u += 0x7FFFu + ((u >> 16) & 1u);   // RNE
    return (unsigned short)(u >> 16);
}
#if __has_builtin(__builtin_amdgcn_cvt_pk_bf16_f32)
typedef __attribute__((ext_vector_type(2))) __bf16 bf16x2_t;
__device__ __forceinline__ unsigned pack2bf(float lo, float hi) {
    bf16x2_t v = __builtin_amdgcn_cvt_pk_bf16_f32(lo, hi);
    unsigned r;
    __builtin_memcpy(&r, &v, 4);
    return r;
}
#else
__device__ __forceinline__ unsigned pack2bf(float lo, float hi) {
    return (unsigned)f2bf(lo) | ((unsigned)f2bf(hi) << 16);
}
#endif
__device__ __forceinline__ float bflo(unsigned p) { return __uint_as_float(p << 16); }
__device__ __forceinline__ float bfhi(unsigned p) { return __uint_as_float(p & 0xFFFF0000u); }

// ---------------- prep: transpose x + pack weights (one launch) ----------------
__global__ __launch_bounds__(256)
void prep_kernel(const float* __restrict__ x, const float* __restrict__ wgt,
                 unsigned short* __restrict__ xt, unsigned short* __restrict__ wpk) {
    const int t = threadIdx.x;
    if (blockIdx.x < 512) {
        __shared__ float tile[WW * 132];
        const int b = blockIdx.x >> 6;
        const int h = blockIdx.x & 63;
        const float* src = x + ((size_t)b * CC * HH + h) * WW;
        {
            const int wq = t & 15;
            const int cb = t >> 4;
#pragma unroll
            for (int it = 0; it < 8; ++it) {
                const int c = it * 16 + cb;
                const float4 v = *reinterpret_cast<const float4*>(src + (size_t)c * (HH * WW) + wq * 4);
                tile[(wq * 4 + 0) * 132 + c] = v.x;
                tile[(wq * 4 + 1) * 132 + c] = v.y;
                tile[(wq * 4 + 2) * 132 + c] = v.z;
                tile[(wq * 4 + 3) * 132 + c] = v.w;
            }
        }
        __syncthreads();
        unsigned short* dst = xt + ((size_t)b * HH + h) * WW * CC;
        {
            const int cg = t & 15;
            const int wb = t >> 4;
#pragma unroll
            for (int it = 0; it < 4; ++it) {
                const int w = it * 16 + wb;
                const float* tp = &tile[w * 132 + cg * 8];
                uint4 p;
                p.x = pack2bf(tp[0], tp[1]);
                p.y = pack2bf(tp[2], tp[3]);
                p.z = pack2bf(tp[4], tp[5]);
                p.w = pack2bf(tp[6], tp[7]);
                *reinterpret_cast<uint4*>(&dst[(size_t)w * CC + cg * 8]) = p;
            }
        }
    } else {
        const int id   = (blockIdx.x - 512) * 256 + t;   // 0..18431
        const int lane = id & 63;
        const int frag = id >> 6;                        // (tap*4 + c0q)*8 + nt
        const int nt   = frag & 7;
        const int c0q  = (frag >> 3) & 3;
        const int tap  = frag >> 5;
        const int o    = (nt << 4) + (lane & 15);
        const int c    = (c0q << 5) + ((lane >> 4) << 3);
        const float* s = wgt + ((size_t)o * CC + c) * KTAPS + tap;
        unsigned u[4];
#pragma unroll
        for (int j = 0; j < 4; ++j)
            u[j] = pack2bf(s[(2 * j) * KTAPS], s[(2 * j + 1) * KTAPS]);
        *reinterpret_cast<uint4*>(wpk + (size_t)frag * 512 + lane * 8) =
            make_uint4(u[0], u[1], u[2], u[3]);
    }
}

// ---------------- main: fused DCN MFMA, 2-wave kh-pair blocks ----------------
__global__ __launch_bounds__(128)
void dcn_mfma_kernel(const unsigned short* __restrict__ xt,
                     const unsigned short* __restrict__ wpk,
                     const float* __restrict__ offset,
                     const float* __restrict__ bias,
                     float* __restrict__ out) {
    __shared__ __align__(16) float2 sLL[KTAPS * 16];      // 1152 B (ly,lx)
    __shared__ __align__(16) short2 sYX[KTAPS * 16];      //  576 B (y0,x0)
    __shared__ __align__(16) float  scr[OO * 21];         // 10752 B reduce/transpose

    const int t   = threadIdx.x;
    const int bid = blockIdx.x;
    const int b   = bid & 7;          // XCD-pinned batch
    const int s   = bid >> 3;         // 0..255
    const int ho  = s >> 2;
    const int mt  = s & 3;            // which 16-wo tile
    const int wobase = mt << 4;

    // ---- sampling records: 9 taps x 16 wo ----
    for (int r = t; r < KTAPS * 16; r += 128) {
        const int k   = r >> 4;
        const int wol = r & 15;
        const int wo  = wobase + wol;
        const int ki  = k / 3;
        const int kj  = k - ki * 3;
        const float dy = offset[(((size_t)b * 18 + 2 * k    ) * 64 + ho) * 64 + wo];
        const float dx = offset[(((size_t)b * 18 + 2 * k + 1) * 64 + ho) * 64 + wo];
        const float py = (float)(ho - 1 + ki) + dy;
        const float px = (float)(wo - 1 + kj) + dx;
        const float y0f = floorf(py);
        const float x0f = floorf(px);
        sLL[r] = make_float2(py - y0f, px - x0f);
        sYX[r] = make_short2((short)(int)y0f, (short)(int)x0f);
    }
    __syncthreads();

    f32x4 acc[8];
#pragma unroll
    for (int nt = 0; nt < 8; ++nt) acc[nt] = (f32x4){0.f, 0.f, 0.f, 0.f};

    const int lane = t & 63;
    const int kh   = t >> 6;          // c-half
    const int lm   = lane & 15;
    const int quad = lane >> 4;
    const char* xb = (const char*)xt + ((size_t)b << 20);   // 1 MiB per batch
    const char* wb = (const char*)wpk;
    const int cbase  = (kh << 7) + (quad << 4);
    const int lane16 = lane << 4;

    for (int tap = 0; tap < KTAPS; ++tap) {
        const int rec = (tap << 4) + lm;
        const float2 ll = sLL[rec];
        const short2 yx = sYX[rec];
        const int y0 = yx.x, x0 = yx.y;
        const int y1 = y0 + 1, x1 = x0 + 1;
        const float ly = ll.x, lx = ll.y;
        const bool vy0 = ((unsigned)y0 < (unsigned)HH);
        const bool vy1 = ((unsigned)y1 < (unsigned)HH);
        const bool vx0 = ((unsigned)x0 < (unsigned)WW);
        const bool vx1 = ((unsigned)x1 < (unsigned)WW);
        const float w00 = (vy0 && vx0) ? (1.f - ly) * (1.f - lx) : 0.f;
        const float w01 = (vy0 && vx1) ? (1.f - ly) * lx         : 0.f;
        const float w10 = (vy1 && vx0) ? ly * (1.f - lx)         : 0.f;
        const float w11 = (vy1 && vx1) ? ly * lx                 : 0.f;
        const int cy0 = min(max(y0, 0), HH - 1);
        const int cy1 = min(max(y1, 0), HH - 1);
        const int cx0 = min(max(x0, 0), WW - 1);
        const int cx1 = min(max(x1, 0), WW - 1);
        const char* base00 = xb + ((((cy0 << 6) + cx0) << 8) + cbase);
        const char* base01 = xb + ((((cy0 << 6) + cx1) << 8) + cbase);
        const char* base10 = xb + ((((cy1 << 6) + cx0) << 8) + cbase);
        const char* base11 = xb + ((((cy1 << 6) + cx1) << 8) + cbase);

        // corner loads for j=0; j=1 prefetched inside the loop
        uint4 a00 = *reinterpret_cast<const uint4*>(base00);
        uint4 a01 = *reinterpret_cast<const uint4*>(base01);
        uint4 a10 = *reinterpret_cast<const uint4*>(base10);
        uint4 a11 = *reinterpret_cast<const uint4*>(base11);

        // frag byte = ((tap*4 + kh*2 + j)*8 + nt)*1024 + lane*16
        const char* wtap = wb + (tap << 15) + (kh << 14) + lane16;

#pragma unroll
        for (int j = 0; j < 2; ++j) {
            uint4 bfr[8];
            const char* wrow = wtap + (j << 13);
#pragma unroll
            for (int nt = 0; nt < 8; ++nt)
                bfr[nt] = *reinterpret_cast<const uint4*>(wrow + (nt << 10));

            uint4 n00, n01, n10, n11;
            if (j == 0) {
                n00 = *reinterpret_cast<const uint4*>(base00 + 64);
                n01 = *reinterpret_cast<const uint4*>(base01 + 64);
                n10 = *reinterpret_cast<const uint4*>(base10 + 64);
                n11 = *reinterpret_cast<const uint4*>(base11 + 64);
            }

            const unsigned* u00 = reinterpret_cast<const unsigned*>(&a00);
            const unsigned* u01 = reinterpret_cast<const unsigned*>(&a01);
            const unsigned* u10 = reinterpret_cast<const unsigned*>(&a10);
            const unsigned* u11 = reinterpret_cast<const unsigned*>(&a11);
            unsigned afu[4];
#pragma unroll
            for (int jj = 0; jj < 4; ++jj) {
                const float rl = w00 * bflo(u00[jj]) + w01 * bflo(u01[jj])
                               + w10 * bflo(u10[jj]) + w11 * bflo(u11[jj]);
                const float rh = w00 * bfhi(u00[jj]) + w01 * bfhi(u01[jj])
                               + w10 * bfhi(u10[jj]) + w11 * bfhi(u11[jj]);
                afu[jj] = pack2bf(rl, rh);
            }
            bf16x8 afrag;
            __builtin_memcpy(&afrag, afu, 16);
#pragma unroll
            for (int nt = 0; nt < 8; ++nt) {
                bf16x8 bfrag;
                __builtin_memcpy(&bfrag, &bfr[nt], 16);
                acc[nt] = __builtin_amdgcn_mfma_f32_16x16x32_bf16(afrag, bfrag, acc[nt], 0, 0, 0);
            }
            if (j == 0) { a00 = n00; a01 = n01; a10 = n10; a11 = n11; }
        }
    }

    // ---- epilogue: kh-reduce in LDS, then transposed 64B-contiguous stores ----
    if (kh == 1) {
#pragma unroll
        for (int nt = 0; nt < 8; ++nt)
            *reinterpret_cast<float4*>(&scr[((nt << 4) + lm) * 21 + (quad << 2)]) =
                make_float4(acc[nt][0], acc[nt][1], acc[nt][2], acc[nt][3]);
    }
    __syncthreads();
    if (kh == 0) {
#pragma unroll
        for (int nt = 0; nt < 8; ++nt) {
            float* p = &scr[((nt << 4) + lm) * 21 + (quad << 2)];
            const float4 v = *reinterpret_cast<const float4*>(p);
            *reinterpret_cast<float4*>(p) =
                make_float4(v.x + acc[nt][0], v.y + acc[nt][1],
                            v.z + acc[nt][2], v.w + acc[nt][3]);
        }
    }
    __syncthreads();
    {
        const int o  = (kh << 6) + lane;    // each wave stores one o-half
        const float bv = bias[o];
        float* op = out + (((size_t)(b * OO + o) * HH + ho) << 6) + wobase;
        const float* sr = scr + o * 21;
#pragma unroll
        for (int jj = 0; jj < 4; ++jj) {
            const float4 f = *reinterpret_cast<const float4*>(sr + jj * 4);
            *reinterpret_cast<float4*>(op + jj * 4) =
                make_float4(f.x + bv, f.y + bv, f.z + bv, f.w + bv);
        }
    }
}

extern "C" void kernel_launch(void* const* d_in, const int* in_sizes, int n_in,
                              void* d_out, int out_size, void* d_ws, size_t ws_size,
                              hipStream_t stream) {
    const float* x      = (const float*)d_in[0];
    const float* offset = (const float*)d_in[1];
    const float* wgt    = (const float*)d_in[2];
    const float* bias   = (const float*)d_in[3];
    float* out = (float*)d_out;

    unsigned short* xt  = (unsigned short*)d_ws;                  // 8 MiB
    unsigned short* wpk = xt + (size_t)BB * HH * WW * CC;         // +288 KiB

    hipLaunchKernelGGL(prep_kernel, dim3(512 + 72), dim3(256), 0, stream, x, wgt, xt, wpk);
    hipLaunchKernelGGL(dcn_mfma_kernel, dim3(BB * HH * 4 * 2 / 2), dim3(128), 0, stream,
                       xt, wpk, offset, bias, out);   // 2048 blocks
}

// Round 9
// 136.157 us; speedup vs baseline: 1.0786x; 1.0309x over previous
//
#include <hip/hip_runtime.h>

// DCNv1 forward on MI355X, bf16 MFMA, round 9: B-weights via double-buffered LDS.
// B=8, C=128, H=W=64, O=128, 3x3, pad=1 -> Ho=Wo=64.
//
// R2..R8 post-mortem: all variants 62-90us, insensitive to occupancy. Constant
// across them: L1 line-request traffic (B-frags from global: 2048 m-tiles x
// 288KB = 590MB = ~36k lines/CU; + scattered gathers ~18k) ~ 23us floor at
// ~1 line/cyc/CU, x stall inefficiency = observed 65-75us. Fix: B staged to LDS
// ONCE per block (32KB/tap, double-buffered, async global_load_lds width=16,
// issued a full tap ahead), read via ds_read_b128 on the separate LDS pipe.
//
// prep_kernel: blocks 0..511: x -> xt[B][H][W][C] bf16; 512..583: wgt -> wpk
//   (frag=(tap*4+c0q)*8+nt, 1KB frags, lane*16B inside).
// dcn_mfma_kernel: grid 512, b=bid&7 (XCD pin), ho=bid>>3. 4 waves = 4 m-tiles
//   (16 wo) x N=128 x full K=1152. One barrier per tap (covers dbuf swap).
//   Epilogue: per-wave LDS transpose (reusing wB) -> 64B-contiguous stores.

#define BB 8
#define CC 128
#define HH 64
#define WW 64
#define OO 128
#define KTAPS 9

typedef __attribute__((ext_vector_type(8))) short bf16x8;
typedef __attribute__((ext_vector_type(4))) float f32x4;

__device__ __forceinline__ unsigned short f2bf(float f) {
    unsigned u = __float_as_uint(f);
    u += 0x7FFFu + ((u >> 16) & 1u);   // RNE
    return (unsigned short)(u >> 16);
}
#if __has_builtin(__builtin_amdgcn_cvt_pk_bf16_f32)
typedef __attribute__((ext_vector_type(2))) __bf16 bf16x2_t;
__device__ __forceinline__ unsigned pack2bf(float lo, float hi) {
    bf16x2_t v = __builtin_amdgcn_cvt_pk_bf16_f32(lo, hi);
    unsigned r;
    __builtin_memcpy(&r, &v, 4);
    return r;
}
#else
__device__ __forceinline__ unsigned pack2bf(float lo, float hi) {
    return (unsigned)f2bf(lo) | ((unsigned)f2bf(hi) << 16);
}
#endif
__device__ __forceinline__ float bflo(unsigned p) { return __uint_as_float(p << 16); }
__device__ __forceinline__ float bfhi(unsigned p) { return __uint_as_float(p & 0xFFFF0000u); }

// ---------------- prep: transpose x + pack weights (one launch) ----------------
__global__ __launch_bounds__(256)
void prep_kernel(const float* __restrict__ x, const float* __restrict__ wgt,
                 unsigned short* __restrict__ xt, unsigned short* __restrict__ wpk) {
    const int t = threadIdx.x;
    if (blockIdx.x < 512) {
        __shared__ float tile[WW * 132];
        const int b = blockIdx.x >> 6;
        const int h = blockIdx.x & 63;
        const float* src = x + ((size_t)b * CC * HH + h) * WW;
        {
            const int wq = t & 15;
            const int cb = t >> 4;
#pragma unroll
            for (int it = 0; it < 8; ++it) {
                const int c = it * 16 + cb;
                const float4 v = *reinterpret_cast<const float4*>(src + (size_t)c * (HH * WW) + wq * 4);
                tile[(wq * 4 + 0) * 132 + c] = v.x;
                tile[(wq * 4 + 1) * 132 + c] = v.y;
                tile[(wq * 4 + 2) * 132 + c] = v.z;
                tile[(wq * 4 + 3) * 132 + c] = v.w;
            }
        }
        __syncthreads();
        unsigned short* dst = xt + ((size_t)b * HH + h) * WW * CC;
        {
            const int cg = t & 15;
            const int wb = t >> 4;
#pragma unroll
            for (int it = 0; it < 4; ++it) {
                const int w = it * 16 + wb;
                const float* tp = &tile[w * 132 + cg * 8];
                uint4 p;
                p.x = pack2bf(tp[0], tp[1]);
                p.y = pack2bf(tp[2], tp[3]);
                p.z = pack2bf(tp[4], tp[5]);
                p.w = pack2bf(tp[6], tp[7]);
                *reinterpret_cast<uint4*>(&dst[(size_t)w * CC + cg * 8]) = p;
            }
        }
    } else {
        const int id   = (blockIdx.x - 512) * 256 + t;   // 0..18431
        const int lane = id & 63;
        const int frag = id >> 6;                        // (tap*4 + c0q)*8 + nt
        const int nt   = frag & 7;
        const int c0q  = (frag >> 3) & 3;
        const int tap  = frag >> 5;
        const int o    = (nt << 4) + (lane & 15);
        const int c    = (c0q << 5) + ((lane >> 4) << 3);
        const float* s = wgt + ((size_t)o * CC + c) * KTAPS + tap;
        unsigned u[4];
#pragma unroll
        for (int j = 0; j < 4; ++j)
            u[j] = pack2bf(s[(2 * j) * KTAPS], s[(2 * j + 1) * KTAPS]);
        *reinterpret_cast<uint4*>(wpk + (size_t)frag * 512 + lane * 8) =
            make_uint4(u[0], u[1], u[2], u[3]);
    }
}

// ---------------- main: fused DCN MFMA, LDS-staged B ----------------
__global__ __launch_bounds__(256, 2)
void dcn_mfma_kernel(const unsigned short* __restrict__ xt,
                     const unsigned short* __restrict__ wpk,
                     const float* __restrict__ offset,
                     const float* __restrict__ bias,
                     float* __restrict__ out) {
    __shared__ __align__(16) unsigned short wB[2][16384];   // 2 x 32 KB B double-buffer
    __shared__ __align__(16) float2 sLL[KTAPS * 64];        // 4608 B (ly,lx)
    __shared__ __align__(16) short2 sYX[KTAPS * 64];        // 2304 B (y0,x0)

    const int t   = threadIdx.x;
    const int bid = blockIdx.x;
    const int b   = bid & 7;          // XCD-pinned batch
    const int ho  = bid >> 3;

    // ---- sampling records: 9 taps x 64 wo ----
    for (int r = t; r < KTAPS * 64; r += 256) {
        const int k  = r >> 6;
        const int wo = r & 63;
        const int ki = k / 3;
        const int kj = k - ki * 3;
        const float dy = offset[(((size_t)b * 18 + 2 * k    ) * 64 + ho) * 64 + wo];
        const float dx = offset[(((size_t)b * 18 + 2 * k + 1) * 64 + ho) * 64 + wo];
        const float py = (float)(ho - 1 + ki) + dy;
        const float px = (float)(wo - 1 + kj) + dx;
        const float y0f = floorf(py);
        const float x0f = floorf(px);
        sLL[r] = make_float2(py - y0f, px - x0f);
        sYX[r] = make_short2((short)(int)y0f, (short)(int)x0f);
    }

    const char* wb = (const char*)wpk;
    // ---- stage tap 0 into buffer 0 (async, direct-to-LDS) ----
    {
        const char* wsrc = wb + (t << 4);
        unsigned short* ldst = &wB[0][t << 3];
#pragma unroll
        for (int i = 0; i < 8; ++i) {
#if __has_builtin(__builtin_amdgcn_global_load_lds)
            __builtin_amdgcn_global_load_lds(
                (const __attribute__((address_space(1))) unsigned*)(wsrc + (i << 12)),
                (__attribute__((address_space(3))) unsigned*)(ldst + (i << 11)), 16, 0, 0);
#else
            *reinterpret_cast<uint4*>(ldst + (i << 11)) =
                *reinterpret_cast<const uint4*>(wsrc + (i << 12));
#endif
        }
    }
    __syncthreads();   // records + tap0 staging complete

    f32x4 acc[8];
#pragma unroll
    for (int nt = 0; nt < 8; ++nt) acc[nt] = (f32x4){0.f, 0.f, 0.f, 0.f};

    const int lane = t & 63;
    const int mi   = t >> 6;          // m-tile (16 wo)
    const int lm   = lane & 15;
    const int quad = lane >> 4;
    const char* xb = (const char*)xt + ((size_t)b << 20);   // 1 MiB per batch
    const int lane8 = lane << 3;      // shorts offset for bfrag

    int curb = 0;
    for (int tap = 0; tap < KTAPS; ++tap) {
        // ---- stage tap+1 into the other buffer (consumed after next barrier) ----
        if (tap < KTAPS - 1) {
            const char* wsrc = wb + ((tap + 1) << 15) + (t << 4);
            unsigned short* ldst = &wB[curb ^ 1][t << 3];
#pragma unroll
            for (int i = 0; i < 8; ++i) {
#if __has_builtin(__builtin_amdgcn_global_load_lds)
                __builtin_amdgcn_global_load_lds(
                    (const __attribute__((address_space(1))) unsigned*)(wsrc + (i << 12)),
                    (__attribute__((address_space(3))) unsigned*)(ldst + (i << 11)), 16, 0, 0);
#else
                *reinterpret_cast<uint4*>(ldst + (i << 11)) =
                    *reinterpret_cast<const uint4*>(wsrc + (i << 12));
#endif
            }
        }

        // ---- decode this lane's sampling record ----
        const int rec = (tap << 6) + (mi << 4) + lm;
        const float2 ll = sLL[rec];
        const short2 yx = sYX[rec];
        const int y0 = yx.x, x0 = yx.y;
        const int y1 = y0 + 1, x1 = x0 + 1;
        const float ly = ll.x, lx = ll.y;
        const bool vy0 = ((unsigned)y0 < (unsigned)HH);
        const bool vy1 = ((unsigned)y1 < (unsigned)HH);
        const bool vx0 = ((unsigned)x0 < (unsigned)WW);
        const bool vx1 = ((unsigned)x1 < (unsigned)WW);
        const float w00 = (vy0 && vx0) ? (1.f - ly) * (1.f - lx) : 0.f;
        const float w01 = (vy0 && vx1) ? (1.f - ly) * lx         : 0.f;
        const float w10 = (vy1 && vx0) ? ly * (1.f - lx)         : 0.f;
        const float w11 = (vy1 && vx1) ? ly * lx                 : 0.f;
        const int cy0 = min(max(y0, 0), HH - 1);
        const int cy1 = min(max(y1, 0), HH - 1);
        const int cx0 = min(max(x0, 0), WW - 1);
        const int cx1 = min(max(x1, 0), WW - 1);
        const char* base00 = xb + ((((cy0 << 6) + cx0) << 8) + (quad << 4));
        const char* base01 = xb + ((((cy0 << 6) + cx1) << 8) + (quad << 4));
        const char* base10 = xb + ((((cy1 << 6) + cx0) << 8) + (quad << 4));
        const char* base11 = xb + ((((cy1 << 6) + cx1) << 8) + (quad << 4));

        // corner loads for c0q=0; next c0q prefetched inside the loop
        uint4 a00 = *reinterpret_cast<const uint4*>(base00);
        uint4 a01 = *reinterpret_cast<const uint4*>(base01);
        uint4 a10 = *reinterpret_cast<const uint4*>(base10);
        uint4 a11 = *reinterpret_cast<const uint4*>(base11);

        const unsigned short* bbuf = wB[curb];

#pragma unroll
        for (int c0q = 0; c0q < 4; ++c0q) {
            // B-frags from LDS (separate pipe from the L1 gather path)
            bf16x8 bfr[8];
#pragma unroll
            for (int nt = 0; nt < 8; ++nt)
                bfr[nt] = *reinterpret_cast<const bf16x8*>(
                    bbuf + (((c0q << 3) + nt) << 9) + lane8);

            uint4 n00, n01, n10, n11;
            if (c0q < 3) {
                const int cb = (c0q + 1) << 6;
                n00 = *reinterpret_cast<const uint4*>(base00 + cb);
                n01 = *reinterpret_cast<const uint4*>(base01 + cb);
                n10 = *reinterpret_cast<const uint4*>(base10 + cb);
                n11 = *reinterpret_cast<const uint4*>(base11 + cb);
            }

            const unsigned* u00 = reinterpret_cast<const unsigned*>(&a00);
            const unsigned* u01 = reinterpret_cast<const unsigned*>(&a01);
            const unsigned* u10 = reinterpret_cast<const unsigned*>(&a10);
            const unsigned* u11 = reinterpret_cast<const unsigned*>(&a11);
            unsigned afu[4];
#pragma unroll
            for (int jj = 0; jj < 4; ++jj) {
                const float rl = w00 * bflo(u00[jj]) + w01 * bflo(u01[jj])
                               + w10 * bflo(u10[jj]) + w11 * bflo(u11[jj]);
                const float rh = w00 * bfhi(u00[jj]) + w01 * bfhi(u01[jj])
                               + w10 * bfhi(u10[jj]) + w11 * bfhi(u11[jj]);
                afu[jj] = pack2bf(rl, rh);
            }
            bf16x8 afrag;
            __builtin_memcpy(&afrag, afu, 16);
#pragma unroll
            for (int nt = 0; nt < 8; ++nt)
                acc[nt] = __builtin_amdgcn_mfma_f32_16x16x32_bf16(afrag, bfr[nt], acc[nt], 0, 0, 0);
            if (c0q < 3) { a00 = n00; a01 = n01; a10 = n10; a11 = n11; }
        }
        __syncthreads();   // all waves done with curb; tap+1 staging drained
        curb ^= 1;
    }

    // ---- epilogue: per-wave LDS transpose (reuse wB) -> 64B-contiguous stores ----
    float* scr = reinterpret_cast<float*>(&wB[0][0]) + mi * 2688;   // 128 o x 21 f32
#pragma unroll
    for (int nt = 0; nt < 8; ++nt) {
        const int o_l = (nt << 4) + lm;
        *reinterpret_cast<float4*>(&scr[o_l * 21 + (quad << 2)]) =
            make_float4(acc[nt][0], acc[nt][1], acc[nt][2], acc[nt][3]);
    }
#pragma unroll
    for (int h = 0; h < 2; ++h) {
        const int o = (h << 6) + lane;
        const float bv = bias[o];
        float* op = out + (((size_t)(b * OO + o) * HH + ho) << 6) + (mi << 4);
        const float* sr = scr + o * 21;
#pragma unroll
        for (int jj = 0; jj < 4; ++jj) {
            const float4 f = *reinterpret_cast<const float4*>(sr + jj * 4);
            *reinterpret_cast<float4*>(op + jj * 4) =
                make_float4(f.x + bv, f.y + bv, f.z + bv, f.w + bv);
        }
    }
}

extern "C" void kernel_launch(void* const* d_in, const int* in_sizes, int n_in,
                              void* d_out, int out_size, void* d_ws, size_t ws_size,
                              hipStream_t stream) {
    const float* x      = (const float*)d_in[0];
    const float* offset = (const float*)d_in[1];
    const float* wgt    = (const float*)d_in[2];
    const float* bias   = (const float*)d_in[3];
    float* out = (float*)d_out;

    unsigned short* xt  = (unsigned short*)d_ws;                  // 8 MiB
    unsigned short* wpk = xt + (size_t)BB * HH * WW * CC;         // +288 KiB

    hipLaunchKernelGGL(prep_kernel, dim3(512 + 72), dim3(256), 0, stream, x, wgt, xt, wpk);
    hipLaunchKernelGGL(dcn_mfma_kernel, dim3(512), dim3(256), 0, stream,
                       xt, wpk, offset, bias, out);
}